// Round 7
// baseline (381.170 us; speedup 1.0000x reference)
//
#include <hip/hip_runtime.h>

typedef __attribute__((ext_vector_type(8))) short short8;
typedef __attribute__((ext_vector_type(4))) float f32x4;

#define N_TOK   16384
#define HDIM    1024
#define OUT_OFF 16777216   // 16384*1024
#define M1ROWS  26216      // 2*(2097+11011)
#define M2ROWS  22022      // 2*11011
#define L2ROW0  4194       // 2*2097

__device__ __forceinline__ unsigned short f2bf(float f) {
  unsigned int u = __float_as_uint(f);
  u += 0x7FFFu + ((u >> 16) & 1u);
  return (unsigned short)(u >> 16);
}

// gathered-row index -> (tensor, rank)
__device__ __forceinline__ void rowmap(int r, int& is_v, int& rank) {
  if (r < 2097)       { is_v = 0; rank = 3276 + r; }
  else if (r < 4194)  { is_v = 1; rank = 1179 + r; }
  else if (r < 15205) { is_v = 0; rank = 1179 + r; }
  else                { is_v = 1; rank = r - 9832; }
}

// ---- stable descending rank: count[i] = #{j : imp[j]>imp[i] or (== and j<i)} ----
__global__ __launch_bounds__(256) void rank_count(const float* __restrict__ imp,
                                                  int* __restrict__ counts) {
  __shared__ float sj[2048];
  const int i = blockIdx.x * 256 + threadIdx.x;
  const int jbase = blockIdx.y * 2048;
  const float vi = imp[i];
  for (int s = threadIdx.x; s < 2048; s += 256) sj[s] = imp[jbase + s];
  __syncthreads();
  int cnt = 0;
  #pragma unroll 8
  for (int s = 0; s < 2048; ++s) {
    float vj = sj[s];
    bool gt = vj > vi;
    bool eq = (vj == vi) && ((jbase + s) < i);
    cnt += (gt || eq) ? 1 : 0;
  }
  atomicAdd(&counts[i], cnt);
}

__global__ __launch_bounds__(256) void scatter_order(const int* __restrict__ counts,
                                                     int* __restrict__ order) {
  int i = blockIdx.x * 256 + threadIdx.x;
  order[counts[i]] = i;
}

// ---- weight convert: dst[N][K] bf16 (transposed, zero-padded) from src[Ksrc][Nsrc] f32 ----
__global__ __launch_bounds__(256) void wconv(unsigned short* __restrict__ dst,
                                             const float* __restrict__ src,
                                             int Nd, int Kd, int Nsrc, int Ksrc) {
  int idx = blockIdx.x * 256 + threadIdx.x;
  if (idx >= Nd * Kd) return;
  int n = idx / Kd, k = idx % Kd;
  float v = (n < Nsrc && k < Ksrc) ? src[k * Nsrc + n] : 0.f;
  dst[idx] = f2bf(v);
}

// ---- gather level>=1 rows into bf16 X (in d_ws) ----
__global__ __launch_bounds__(256) void gather_rows(unsigned short* __restrict__ X,
                                                   const float* __restrict__ keys,
                                                   const float* __restrict__ values,
                                                   const int* __restrict__ order) {
  int r = blockIdx.x;
  int is_v, rank; rowmap(r, is_v, rank);
  int token = order[rank];
  const float* src = (is_v ? values : keys) + (size_t)token * HDIM;
  int c = threadIdx.x * 4;
  float4 f = *reinterpret_cast<const float4*>(src + c);
  ushort4 h;
  h.x = f2bf(f.x); h.y = f2bf(f.y); h.z = f2bf(f.z); h.w = f2bf(f.w);
  *reinterpret_cast<ushort4*>(X + (size_t)r * HDIM + c) = h;
}

// ---- level 0: exact f32 passthrough ----
__global__ __launch_bounds__(256) void copy_level0(float* __restrict__ out,
                                                   const float* __restrict__ keys,
                                                   const float* __restrict__ values,
                                                   const int* __restrict__ order) {
  int b = blockIdx.x;
  int is_v = b & 1, rank = b >> 1;
  int token = order[rank];
  const float* src = (is_v ? values : keys) + (size_t)token * HDIM;
  float* dst = out + (is_v ? OUT_OFF : 0) + (size_t)token * HDIM;
  int c = threadIdx.x * 4;
  *reinterpret_cast<float4*>(dst + c) = *reinterpret_cast<const float4*>(src + c);
}

#define GLDS16(g, l) __builtin_amdgcn_global_load_lds( \
    (const __attribute__((address_space(1))) void*)(g), \
    (__attribute__((address_space(3))) void*)(l), 16, 0, 0)

// ---- B-stationary GEMM: C = relu(A @ B + bias); Bt transposed [N][K] ----
// Block stages its BN x K weight panel into LDS ONCE (one barrier), then 8
// waves run independent barrier-free K-streams:
//   per K32: MFR global A-loads (depth-2 reg pipeline via renaming)
//          + NFR ds_read_b128 (XOR slot^ (row&7) swizzle, conflict-free)
//          + MFR*NFR MFMA.
// Wave tile = 64 rows x BN cols; BM = 512 rows/block.
// XCD-bijective swizzle pins all col-panels of an M-panel to one XCD, so
// A re-reads across col-panels hit that XCD's L2.
// MODE 0: bf16 store to Cbf (ldc), guard c<N. MODE 1: f32 scatter via rowmap.
template<int MODE, int MFR, int NFR, int K>
__global__ __launch_bounds__(512) void bstat_gemm(
    const unsigned short* __restrict__ A, int M,
    const unsigned short* __restrict__ Bt, int N,
    const float* __restrict__ bias, int Nbias,
    unsigned short* __restrict__ Cbf, int ldc,
    float* __restrict__ outf, const int* __restrict__ order,
    int NP, int NC) {
  constexpr int BN = NFR * 16;
  constexpr int CH = K / 8;                      // 16B chunks per B row
  __shared__ __align__(16) unsigned short Blds[BN * K];

  const int bid = blockIdx.x;
  const int r8 = bid & 7, rest = bid >> 3;
  const int c8 = rest % NC, q8 = rest / NC;
  const int p8 = q8 * 8 + r8;
  if (p8 >= NP) return;
  const int row0 = p8 * 512;
  const int col0 = c8 * BN;

  const int tid = threadIdx.x;
  const int wave = tid >> 6, lane = tid & 63;
  const int fr = lane & 15, lch = lane >> 4;

  // ---- stage B panel (linear LDS dest, pre-swizzled global source) ----
  constexpr int ROUNDS = (BN * K * 2) / 8192;    // 1 KB per wave-instr
  #pragma unroll
  for (int j = 0; j < ROUNDS; ++j) {
    int off16 = (j * 8 + wave) * 64 + lane;      // physical 16B slot index
    int brow = off16 / CH;
    int bslot = off16 % CH;
    int bsrc = bslot ^ (brow & 7);               // content chunk (involution)
    int gr = col0 + brow; if (gr >= N) gr = 0;
    GLDS16(Bt + (size_t)gr * K + bsrc * 8, Blds + (size_t)off16 * 8);
  }
  asm volatile("s_waitcnt vmcnt(0)" ::: "memory");
  __syncthreads();                               // the ONLY barrier

  // ---- per-wave A row pointers ----
  const int arow = row0 + wave * 64;
  const unsigned short* ap[MFR];
  #pragma unroll
  for (int m = 0; m < MFR; ++m) {
    int rr = arow + m * 16 + fr; if (rr >= M) rr = 0;
    ap[m] = A + (size_t)rr * K + lch * 8;
  }

  f32x4 acc[MFR][NFR] = {};
  constexpr int NT = K / 32;
  short8 a0[MFR], a1[MFR];
  #pragma unroll
  for (int m = 0; m < MFR; ++m) a0[m] = *reinterpret_cast<const short8*>(ap[m]);
  #pragma unroll
  for (int m = 0; m < MFR; ++m) a1[m] = *reinterpret_cast<const short8*>(ap[m] + 32);

  #pragma unroll 1
  for (int t = 0; t < NT; t += 2) {
    short8 b[NFR];
    #pragma unroll
    for (int n = 0; n < NFR; ++n) {
      int brow = n * 16 + fr;
      int pc = (4 * t + lch) ^ (brow & 7);
      b[n] = *reinterpret_cast<const short8*>(Blds + brow * K + pc * 8);
    }
    #pragma unroll
    for (int m = 0; m < MFR; ++m)
      #pragma unroll
      for (int n = 0; n < NFR; ++n)
        acc[m][n] = __builtin_amdgcn_mfma_f32_16x16x32_bf16(a0[m], b[n], acc[m][n], 0, 0, 0);
    if (t + 2 < NT) {
      #pragma unroll
      for (int m = 0; m < MFR; ++m)
        a0[m] = *reinterpret_cast<const short8*>(ap[m] + (t + 2) * 32);
    }
    #pragma unroll
    for (int n = 0; n < NFR; ++n) {
      int brow = n * 16 + fr;
      int pc = (4 * (t + 1) + lch) ^ (brow & 7);
      b[n] = *reinterpret_cast<const short8*>(Blds + brow * K + pc * 8);
    }
    #pragma unroll
    for (int m = 0; m < MFR; ++m)
      #pragma unroll
      for (int n = 0; n < NFR; ++n)
        acc[m][n] = __builtin_amdgcn_mfma_f32_16x16x32_bf16(a1[m], b[n], acc[m][n], 0, 0, 0);
    if (t + 3 < NT) {
      #pragma unroll
      for (int m = 0; m < MFR; ++m)
        a1[m] = *reinterpret_cast<const short8*>(ap[m] + (t + 3) * 32);
    }
  }

  // ---- epilogue ----
  const int orow = lch * 4;
  #pragma unroll
  for (int m = 0; m < MFR; ++m) {
    #pragma unroll
    for (int n = 0; n < NFR; ++n) {
      #pragma unroll
      for (int j = 0; j < 4; ++j) {
        int r = arow + m * 16 + orow + j;
        int c = col0 + n * 16 + fr;
        if (r < M && c < N) {
          float v = acc[m][n][j] + (c < Nbias ? bias[c] : 0.f);
          v = fmaxf(v, 0.f);
          if (MODE == 0) {
            Cbf[(size_t)r * ldc + c] = f2bf(v);
          } else {
            int iv, rk; rowmap(r, iv, rk);
            int token = order[rk];
            outf[(size_t)(iv ? OUT_OFF : 0) + (size_t)token * HDIM + c] = v;
          }
        }
      }
    }
  }
}

static inline int swzg(int NP, int NC) { return 8 * NC * ((NP + 7) / 8); }

extern "C" void kernel_launch(void* const* d_in, const int* in_sizes, int n_in,
                              void* d_out, int out_size, void* d_ws, size_t ws_size,
                              hipStream_t stream) {
  const float* keys   = (const float*)d_in[0];
  const float* values = (const float*)d_in[1];
  const float* imp    = (const float*)d_in[2];
  const float* We0    = (const float*)d_in[3];
  const float* be0    = (const float*)d_in[4];
  const float* We1    = (const float*)d_in[5];
  const float* be1    = (const float*)d_in[6];
  const float* Wd0    = (const float*)d_in[7];
  const float* bd0    = (const float*)d_in[8];
  const float* Wd1    = (const float*)d_in[9];
  const float* bd1    = (const float*)d_in[10];

  char* ws = (char*)d_ws;
  int* counts           = (int*)(ws);                       // 64 KB
  int* order            = (int*)(ws + 65536);               // 64 KB
  unsigned short* We0T  = (unsigned short*)(ws + 131072);   // [512][1024]
  unsigned short* We1T  = (unsigned short*)(ws + 1179648);  // [256][512] zero-pad rows 204..255
  unsigned short* Wd1T  = (unsigned short*)(ws + 1441792);  // [512][256] zero-pad cols 204..255
  unsigned short* Wd0T  = (unsigned short*)(ws + 1703936);  // [1024][512]
  unsigned short* Y     = (unsigned short*)(ws + 2752512);  // [26216][512]
  unsigned short* Z     = (unsigned short*)(ws + 29597696); // [22022][256] (pad cols exact 0)
  unsigned short* X     = (unsigned short*)(ws + 40872960); // [26216][1024]
  float* outf = (float*)d_out;

  hipMemsetAsync(counts, 0, 65536, stream);
  rank_count<<<dim3(64, 8), 256, 0, stream>>>(imp, counts);
  scatter_order<<<64, 256, 0, stream>>>(counts, order);

  wconv<<<2048, 256, 0, stream>>>(We0T, We0, 512, 1024, 512, 1024);
  wconv<<<512,  256, 0, stream>>>(We1T, We1, 256, 512, 204, 512);
  wconv<<<512,  256, 0, stream>>>(Wd1T, Wd1, 512, 256, 512, 204);
  wconv<<<2048, 256, 0, stream>>>(Wd0T, Wd0, 1024, 512, 1024, 512);

  gather_rows<<<M1ROWS, 256, 0, stream>>>(X, keys, values, order);
  copy_level0<<<6552, 256, 0, stream>>>(outf, keys, values, order);

  // GEMM1: Y = relu(X @ We0 + be0)   [26216 x 1024] x [1024 x 512]  (BN=64)
  bstat_gemm<0, 4, 4, 1024><<<swzg(52, 8), 512, 0, stream>>>(
      X, M1ROWS, We0T, 512, be0, 512, Y, 512, nullptr, nullptr, 52, 8);

  // GEMM2a: Z = relu(Y_l2 @ We1 + be1)  [22022 x 512] x [512 x 256(pad)] -> pads exact 0
  bstat_gemm<0, 4, 8, 512><<<swzg(44, 2), 512, 0, stream>>>(
      Y + (size_t)L2ROW0 * 512, M2ROWS, We1T, 256, be1, 204, Z, 256,
      nullptr, nullptr, 44, 2);

  // GEMM2b: Y_l2 = relu(Z @ Wd1 + bd1)  [22022 x 256pad] x [256 x 512]
  bstat_gemm<0, 4, 8, 256><<<swzg(44, 4), 512, 0, stream>>>(
      Z, M2ROWS, Wd1T, 512, bd1, 512, Y + (size_t)L2ROW0 * 512, 512,
      nullptr, nullptr, 44, 4);

  // GEMM3: out = relu(Y @ Wd0 + bd0), scattered f32  [26216 x 512] x [512 x 1024]
  bstat_gemm<1, 4, 8, 512><<<swzg(52, 8), 512, 0, stream>>>(
      Y, M1ROWS, Wd0T, 1024, bd0, 1024, nullptr, 0, outf, order, 52, 8);
}

// Round 8
// 348.939 us; speedup vs baseline: 1.0924x; 1.0924x over previous
//
#include <hip/hip_runtime.h>

typedef __attribute__((ext_vector_type(8))) short short8;
typedef __attribute__((ext_vector_type(4))) float f32x4;

#define N_TOK   16384
#define HDIM    1024
#define OUT_OFF 16777216   // 16384*1024
#define M1ROWS  26216      // 2*(2097+11011)
#define M2ROWS  22022      // 2*11011
#define L2ROW0  4194       // 2*2097

__device__ __forceinline__ unsigned short f2bf(float f) {
  unsigned int u = __float_as_uint(f);
  u += 0x7FFFu + ((u >> 16) & 1u);
  return (unsigned short)(u >> 16);
}

__device__ __forceinline__ void rowmap(int r, int& is_v, int& rank) {
  if (r < 2097)       { is_v = 0; rank = 3276 + r; }
  else if (r < 4194)  { is_v = 1; rank = 1179 + r; }
  else if (r < 15205) { is_v = 0; rank = 1179 + r; }
  else                { is_v = 1; rank = r - 9832; }
}

// ---- stable descending rank ----
__global__ __launch_bounds__(256) void rank_count(const float* __restrict__ imp,
                                                  int* __restrict__ counts) {
  __shared__ float sj[2048];
  const int i = blockIdx.x * 256 + threadIdx.x;
  const int jbase = blockIdx.y * 2048;
  const float vi = imp[i];
  for (int s = threadIdx.x; s < 2048; s += 256) sj[s] = imp[jbase + s];
  __syncthreads();
  int cnt = 0;
  #pragma unroll 8
  for (int s = 0; s < 2048; ++s) {
    float vj = sj[s];
    bool gt = vj > vi;
    bool eq = (vj == vi) && ((jbase + s) < i);
    cnt += (gt || eq) ? 1 : 0;
  }
  atomicAdd(&counts[i], cnt);
}

__global__ __launch_bounds__(256) void scatter_order(const int* __restrict__ counts,
                                                     int* __restrict__ order) {
  int i = blockIdx.x * 256 + threadIdx.x;
  order[counts[i]] = i;
}

// ---- weight convert: dst[N][K] bf16 (transposed, zero-padded) ----
__global__ __launch_bounds__(256) void wconv(unsigned short* __restrict__ dst,
                                             const float* __restrict__ src,
                                             int Nd, int Kd, int Nsrc, int Ksrc) {
  int idx = blockIdx.x * 256 + threadIdx.x;
  if (idx >= Nd * Kd) return;
  int n = idx / Kd, k = idx % Kd;
  float v = (n < Nsrc && k < Ksrc) ? src[k * Nsrc + n] : 0.f;
  dst[idx] = f2bf(v);
}

__global__ __launch_bounds__(256) void gather_rows(unsigned short* __restrict__ X,
                                                   const float* __restrict__ keys,
                                                   const float* __restrict__ values,
                                                   const int* __restrict__ order) {
  int r = blockIdx.x;
  int is_v, rank; rowmap(r, is_v, rank);
  int token = order[rank];
  const float* src = (is_v ? values : keys) + (size_t)token * HDIM;
  int c = threadIdx.x * 4;
  float4 f = *reinterpret_cast<const float4*>(src + c);
  ushort4 h;
  h.x = f2bf(f.x); h.y = f2bf(f.y); h.z = f2bf(f.z); h.w = f2bf(f.w);
  *reinterpret_cast<ushort4*>(X + (size_t)r * HDIM + c) = h;
}

__global__ __launch_bounds__(256) void copy_level0(float* __restrict__ out,
                                                   const float* __restrict__ keys,
                                                   const float* __restrict__ values,
                                                   const int* __restrict__ order) {
  int b = blockIdx.x;
  int is_v = b & 1, rank = b >> 1;
  int token = order[rank];
  const float* src = (is_v ? values : keys) + (size_t)token * HDIM;
  float* dst = out + (is_v ? OUT_OFF : 0) + (size_t)token * HDIM;
  int c = threadIdx.x * 4;
  *reinterpret_cast<float4*>(dst + c) = *reinterpret_cast<const float4*>(src + c);
}

#define GLDS16(g, l) __builtin_amdgcn_global_load_lds( \
    (const __attribute__((address_space(1))) void*)(g), \
    (__attribute__((address_space(3))) void*)(l), 16, 0, 0)

// ---- m201-faithful 256x256 GEMM: C = relu(A @ B + bias); Bt is [N][K] ----
// BM=BN=256, BK=64, 8 waves (2M x 4N), per-wave 128x64 output.
// LDS = 4 half-K-tile slots x (A-slab[256][32] + B-slab[256][32]) = 128 KB.
// 64-B slab row stride + R4-proven XOR swizzle (phys chunk = content ^
// ((row>>1)&3), via pre-swizzled global source; measured 0 conflicts).
// Per half-tile, 2 phases; per phase: {ds_reads || 2 global_load_lds ->
// barrier -> lgkmcnt(0) -> sched_barrier -> setprio(1) -> 16 MFMA ->
// setprio(0) -> barrier}. vmcnt(8) once per half-tile: 2 half-tiles stay
// in flight, 3 staged ahead (slot h+3 == slot h-1, freed). Never drain 0.
// MODE 0: bf16 store. MODE 1: f32 scatter via rowmap/order.
template<int MODE, int K>
__global__ __launch_bounds__(512, 2) void g256(
    const unsigned short* __restrict__ A, int M,
    const unsigned short* __restrict__ Bt, int N,
    const float* __restrict__ bias, int Nbias,
    unsigned short* __restrict__ Cbf, int ldc,
    float* __restrict__ outf, const int* __restrict__ order,
    int NP, int NC) {
  constexpr int NH = K / 32;                 // half-K-tiles
  __shared__ __align__(16) unsigned short S[4][16384];

  const int bid = blockIdx.x;
  const int r8 = bid & 7, rest = bid >> 3;
  const int c8 = rest % NC, q8 = rest / NC;
  const int p8 = q8 * 8 + r8;
  if (p8 >= NP) return;
  const int row0 = p8 * 256, col0 = c8 * 256;

  const int tid = threadIdx.x;
  const int wave = tid >> 6, lane = tid & 63;
  const int wm = wave >> 2, wn = wave & 3;
  const int fr = lane & 15, lch = lane >> 4;

  // staging geometry: wave-instr = 16 rows x 64 B; lane -> (row lrow, slot lane&3)
  const int lrow = lane >> 2;
  const int sswz = (((lane & 3) ^ ((lrow >> 1) & 3)) << 3);  // content col (shorts)
  int ar0 = row0 + (wave * 2 + 0) * 16 + lrow; if (ar0 >= M) ar0 = 0;
  int ar1 = row0 + (wave * 2 + 1) * 16 + lrow; if (ar1 >= M) ar1 = 0;
  const unsigned short* ag0 = A + (size_t)ar0 * K + sswz;
  const unsigned short* ag1 = A + (size_t)ar1 * K + sswz;
  const unsigned short* bg0 = Bt + (size_t)(col0 + (wave * 2 + 0) * 16 + lrow) * K + sswz;
  const unsigned short* bg1 = Bt + (size_t)(col0 + (wave * 2 + 1) * 16 + lrow) * K + sswz;
  const int adst = (wave * 2) * 512;         // shorts, within slot
  const int bdst = 8192 + (wave * 2) * 512;

  // fragment-read geometry (R4-proven): phys chunk = lch ^ ((fr>>1)&3)
  const int qoff = ((lch ^ ((fr >> 1) & 3)) << 3);
  const int abase = (wm * 128 + fr) * 32 + qoff;
  const int bbase = 8192 + (wn * 64 + fr) * 32 + qoff;

  f32x4 acc[8][4] = {};

  // prologue: stage half-tiles 0,1,2 (12 loads; 4 per half per wave)
  #pragma unroll
  for (int h = 0; h < 3; ++h) {
    unsigned short* sl = (unsigned short*)S + h * 16384;
    GLDS16(ag0 + h * 32, sl + adst);
    GLDS16(ag1 + h * 32, sl + adst + 512);
    GLDS16(bg0 + h * 32, sl + bdst);
    GLDS16(bg1 + h * 32, sl + bdst + 512);
  }
  asm volatile("s_waitcnt vmcnt(8)" ::: "memory");   // half 0 landed
  __builtin_amdgcn_s_barrier();

  #pragma unroll 1
  for (int h = 0; h < NH; ++h) {
    const unsigned short* sl = (const unsigned short*)S + (h & 3) * 16384;
    unsigned short* dl = (unsigned short*)S + ((h + 3) & 3) * 16384;
    const bool pf = (h + 3 < NH);
    const int kc = (h + 3) * 32;
    short8 a[8], b0, b1;
    // ======== phase 0: read A(8) + B n0,n1; stage 2 A-loads; MFMA n0,n1 ========
    #pragma unroll
    for (int m = 0; m < 8; ++m)
      a[m] = *reinterpret_cast<const short8*>(sl + abase + m * 512);
    b0 = *reinterpret_cast<const short8*>(sl + bbase);
    b1 = *reinterpret_cast<const short8*>(sl + bbase + 512);
    if (pf) { GLDS16(ag0 + kc, dl + adst); GLDS16(ag1 + kc, dl + adst + 512); }
    __builtin_amdgcn_s_barrier();
    asm volatile("s_waitcnt lgkmcnt(0)" ::: "memory");
    __builtin_amdgcn_sched_barrier(0);
    __builtin_amdgcn_s_setprio(1);
    #pragma unroll
    for (int m = 0; m < 8; ++m)
      acc[m][0] = __builtin_amdgcn_mfma_f32_16x16x32_bf16(a[m], b0, acc[m][0], 0, 0, 0);
    #pragma unroll
    for (int m = 0; m < 8; ++m)
      acc[m][1] = __builtin_amdgcn_mfma_f32_16x16x32_bf16(a[m], b1, acc[m][1], 0, 0, 0);
    __builtin_amdgcn_s_setprio(0);
    __builtin_amdgcn_s_barrier();
    // ======== phase 1: read B n2,n3; stage 2 B-loads; MFMA n2,n3 ========
    b0 = *reinterpret_cast<const short8*>(sl + bbase + 1024);
    b1 = *reinterpret_cast<const short8*>(sl + bbase + 1536);
    if (pf) { GLDS16(bg0 + kc, dl + bdst); GLDS16(bg1 + kc, dl + bdst + 512); }
    __builtin_amdgcn_s_barrier();
    asm volatile("s_waitcnt lgkmcnt(0)" ::: "memory");
    __builtin_amdgcn_sched_barrier(0);
    __builtin_amdgcn_s_setprio(1);
    #pragma unroll
    for (int m = 0; m < 8; ++m)
      acc[m][2] = __builtin_amdgcn_mfma_f32_16x16x32_bf16(a[m], b0, acc[m][2], 0, 0, 0);
    #pragma unroll
    for (int m = 0; m < 8; ++m)
      acc[m][3] = __builtin_amdgcn_mfma_f32_16x16x32_bf16(a[m], b1, acc[m][3], 0, 0, 0);
    __builtin_amdgcn_s_setprio(0);
    if (h + 3 < NH)      asm volatile("s_waitcnt vmcnt(8)" ::: "memory"); // h+1 landed
    else if (h + 2 < NH) asm volatile("s_waitcnt vmcnt(4)" ::: "memory");
    else if (h + 1 < NH) asm volatile("s_waitcnt vmcnt(0)" ::: "memory");
    __builtin_amdgcn_s_barrier();
  }

  // ---- epilogue ----
  const int orow = lch * 4;
  #pragma unroll
  for (int m = 0; m < 8; ++m) {
    #pragma unroll
    for (int n = 0; n < 4; ++n) {
      #pragma unroll
      for (int j = 0; j < 4; ++j) {
        int r = row0 + wm * 128 + m * 16 + orow + j;
        int c = col0 + wn * 64 + n * 16 + fr;
        if (r < M && c < N) {
          float v = acc[m][n][j] + (c < Nbias ? bias[c] : 0.f);
          v = fmaxf(v, 0.f);
          if (MODE == 0) {
            Cbf[(size_t)r * ldc + c] = f2bf(v);
          } else {
            int iv, rk; rowmap(r, iv, rk);
            int token = order[rk];
            outf[(size_t)(iv ? OUT_OFF : 0) + (size_t)token * HDIM + c] = v;
          }
        }
      }
    }
  }
}

static inline int swzg(int NP, int NC) { return 8 * NC * ((NP + 7) / 8); }

extern "C" void kernel_launch(void* const* d_in, const int* in_sizes, int n_in,
                              void* d_out, int out_size, void* d_ws, size_t ws_size,
                              hipStream_t stream) {
  const float* keys   = (const float*)d_in[0];
  const float* values = (const float*)d_in[1];
  const float* imp    = (const float*)d_in[2];
  const float* We0    = (const float*)d_in[3];
  const float* be0    = (const float*)d_in[4];
  const float* We1    = (const float*)d_in[5];
  const float* be1    = (const float*)d_in[6];
  const float* Wd0    = (const float*)d_in[7];
  const float* bd0    = (const float*)d_in[8];
  const float* Wd1    = (const float*)d_in[9];
  const float* bd1    = (const float*)d_in[10];

  char* ws = (char*)d_ws;
  int* counts           = (int*)(ws);                       // 64 KB
  int* order            = (int*)(ws + 65536);               // 64 KB
  unsigned short* We0T  = (unsigned short*)(ws + 131072);   // [512][1024]
  unsigned short* We1T  = (unsigned short*)(ws + 1179648);  // [256][512], rows 204+ zero
  unsigned short* Wd1T  = (unsigned short*)(ws + 1441792);  // [512][256], cols 204+ zero
  unsigned short* Wd0T  = (unsigned short*)(ws + 1703936);  // [1024][512]
  unsigned short* Y     = (unsigned short*)(ws + 2752512);  // [26216][512]
  unsigned short* Z     = (unsigned short*)(ws + 29597696); // [22022][256]
  unsigned short* X     = (unsigned short*)(ws + 40872960); // [26216][1024]
  float* outf = (float*)d_out;

  hipMemsetAsync(counts, 0, 65536, stream);
  rank_count<<<dim3(64, 8), 256, 0, stream>>>(imp, counts);
  scatter_order<<<64, 256, 0, stream>>>(counts, order);

  wconv<<<2048, 256, 0, stream>>>(We0T, We0, 512, 1024, 512, 1024);
  wconv<<<512,  256, 0, stream>>>(We1T, We1, 256, 512, 204, 512);
  wconv<<<512,  256, 0, stream>>>(Wd1T, Wd1, 512, 256, 512, 204);
  wconv<<<2048, 256, 0, stream>>>(Wd0T, Wd0, 1024, 512, 1024, 512);

  gather_rows<<<M1ROWS, 256, 0, stream>>>(X, keys, values, order);
  copy_level0<<<6552, 256, 0, stream>>>(outf, keys, values, order);

  // GEMM1: Y = relu(X @ We0 + be0)   [26216 x 1024] x [1024 x 512]
  g256<0, 1024><<<swzg(103, 2), 512, 0, stream>>>(
      X, M1ROWS, We0T, 512, be0, 512, Y, 512, nullptr, nullptr, 103, 2);

  // GEMM2a: Z = relu(Y_l2 @ We1 + be1)  [22022 x 512] x [512 x 256pad]
  // (We1T rows 204..255 are zero -> pad cols of Z come out exactly 0)
  g256<0, 512><<<swzg(87, 1), 512, 0, stream>>>(
      Y + (size_t)L2ROW0 * 512, M2ROWS, We1T, 256, be1, 204, Z, 256,
      nullptr, nullptr, 87, 1);

  // GEMM2b: Y_l2 = relu(Z @ Wd1 + bd1)  [22022 x 256] x [256 x 512]
  // (Wd1T cols 204..255 are zero -> Z pad cols contribute nothing)
  g256<0, 256><<<swzg(87, 2), 512, 0, stream>>>(
      Z, M2ROWS, Wd1T, 512, bd1, 512, Y + (size_t)L2ROW0 * 512, 512,
      nullptr, nullptr, 87, 2);

  // GEMM3: out = relu(Y @ Wd0 + bd0), scattered f32  [26216 x 512] x [512 x 1024]
  g256<1, 512><<<swzg(103, 4), 512, 0, stream>>>(
      Y, M1ROWS, Wd0T, 1024, bd0, 1024, nullptr, 0, outf, order, 103, 4);
}

// Round 9
// 276.607 us; speedup vs baseline: 1.3780x; 1.2615x over previous
//
#include <hip/hip_runtime.h>

typedef __attribute__((ext_vector_type(8))) short short8;
typedef __attribute__((ext_vector_type(4))) float f32x4;

#define N_TOK   16384
#define HDIM    1024
#define OUT_OFF 16777216   // 16384*1024
#define M1ROWS  26216      // 2*(2097+11011)
#define M2ROWS  22022      // 2*11011
#define L2ROW0  4194       // 2*2097

__device__ __forceinline__ unsigned short f2bf(float f) {
  unsigned int u = __float_as_uint(f);
  u += 0x7FFFu + ((u >> 16) & 1u);
  return (unsigned short)(u >> 16);
}

__device__ __forceinline__ void rowmap(int r, int& is_v, int& rank) {
  if (r < 2097)       { is_v = 0; rank = 3276 + r; }
  else if (r < 4194)  { is_v = 1; rank = 1179 + r; }
  else if (r < 15205) { is_v = 0; rank = 1179 + r; }
  else                { is_v = 1; rank = r - 9832; }
}

// ---- stable descending rank ----
__global__ __launch_bounds__(256) void rank_count(const float* __restrict__ imp,
                                                  int* __restrict__ counts) {
  __shared__ float sj[2048];
  const int i = blockIdx.x * 256 + threadIdx.x;
  const int jbase = blockIdx.y * 2048;
  const float vi = imp[i];
  for (int s = threadIdx.x; s < 2048; s += 256) sj[s] = imp[jbase + s];
  __syncthreads();
  int cnt = 0;
  #pragma unroll 8
  for (int s = 0; s < 2048; ++s) {
    float vj = sj[s];
    bool gt = vj > vi;
    bool eq = (vj == vi) && ((jbase + s) < i);
    cnt += (gt || eq) ? 1 : 0;
  }
  atomicAdd(&counts[i], cnt);
}

__global__ __launch_bounds__(256) void scatter_order(const int* __restrict__ counts,
                                                     int* __restrict__ order) {
  int i = blockIdx.x * 256 + threadIdx.x;
  order[counts[i]] = i;
}

// ---- weight convert: dst[N][K] bf16 (transposed, zero-padded) ----
__global__ __launch_bounds__(256) void wconv(unsigned short* __restrict__ dst,
                                             const float* __restrict__ src,
                                             int Nd, int Kd, int Nsrc, int Ksrc) {
  int idx = blockIdx.x * 256 + threadIdx.x;
  if (idx >= Nd * Kd) return;
  int n = idx / Kd, k = idx % Kd;
  float v = (n < Nsrc && k < Ksrc) ? src[k * Nsrc + n] : 0.f;
  dst[idx] = f2bf(v);
}

__global__ __launch_bounds__(256) void gather_rows(unsigned short* __restrict__ X,
                                                   const float* __restrict__ keys,
                                                   const float* __restrict__ values,
                                                   const int* __restrict__ order) {
  int r = blockIdx.x;
  int is_v, rank; rowmap(r, is_v, rank);
  int token = order[rank];
  const float* src = (is_v ? values : keys) + (size_t)token * HDIM;
  int c = threadIdx.x * 4;
  float4 f = *reinterpret_cast<const float4*>(src + c);
  ushort4 h;
  h.x = f2bf(f.x); h.y = f2bf(f.y); h.z = f2bf(f.z); h.w = f2bf(f.w);
  *reinterpret_cast<ushort4*>(X + (size_t)r * HDIM + c) = h;
}

__global__ __launch_bounds__(256) void copy_level0(float* __restrict__ out,
                                                   const float* __restrict__ keys,
                                                   const float* __restrict__ values,
                                                   const int* __restrict__ order) {
  int b = blockIdx.x;
  int is_v = b & 1, rank = b >> 1;
  int token = order[rank];
  const float* src = (is_v ? values : keys) + (size_t)token * HDIM;
  float* dst = out + (is_v ? OUT_OFF : 0) + (size_t)token * HDIM;
  int c = threadIdx.x * 4;
  *reinterpret_cast<float4*>(dst + c) = *reinterpret_cast<const float4*>(src + c);
}

#define GLDS16(g, l) __builtin_amdgcn_global_load_lds( \
    (const __attribute__((address_space(1))) void*)(g), \
    (__attribute__((address_space(3))) void*)(l), 16, 0, 0)

// ---- tiled bf16 GEMM: C = relu(A @ B + bias); Bt is [N][K] ----
// 256x128 tile, 8 waves (4M x 2N, wave tile 64x64), BK=32 half-tiles,
// 3-slot LDS ring (72 KB -> 2 blocks/CU = 4 waves/SIMD: co-resident block
// fills the other's stalls). Per half-tile:
//   {8x ds_read_b128 -> lgkmcnt(0) -> sched_barrier -> barrier ->
//    setprio(1) -> 16 MFMA -> setprio(0) ->
//    issue 3 global_load_lds for half h+3 (same slot; safe: all waves'
//    ds_reads completed before the pre-MFMA barrier) ->
//    vmcnt(6) (h+1 landed; never 0 mid-loop) -> barrier}.
// R4-proven XOR swizzle (0 measured conflicts): 64-B slab rows, phys
// chunk = content ^ ((row>>1)&3), via pre-swizzled global source.
// XCD-bijective block swizzle: panel p pinned to XCD p%8.
// MODE 0: bf16 store. MODE 1: LDS-staged f32x4 scatter via rowmap/order.
template<int MODE, int K>
__global__ __launch_bounds__(512, 4) void g2(
    const unsigned short* __restrict__ A, int M,
    const unsigned short* __restrict__ Bt, int N,
    const float* __restrict__ bias, int Nbias,
    unsigned short* __restrict__ Cbf, int ldc,
    float* __restrict__ outf, const int* __restrict__ order,
    int NP, int NC) {
  constexpr int NH = K / 32;
  __shared__ __align__(16) unsigned short S[3][12288];   // slot: A[256][32]+B[128][32]

  const int bid = blockIdx.x;
  const int r8 = bid & 7, rest = bid >> 3;
  const int c8 = rest % NC, q8 = rest / NC;
  const int p8 = q8 * 8 + r8;
  if (p8 >= NP) return;
  const int row0 = p8 * 256, col0 = c8 * 128;

  const int tid = threadIdx.x;
  const int wave = tid >> 6, lane = tid & 63;
  const int wm = wave >> 1, wn = wave & 1;
  const int fr = lane & 15, lch = lane >> 4;

  // staging: 24 segs of 16 rows (A 0..15, B 16..23); 3 loads/wave/half
  const int lrow = lane >> 2;
  const int sswz = (((lane & 3) ^ ((lane >> 3) & 3)) << 3);
  const unsigned short* gp[3];
  int ldso[3];
  #pragma unroll
  for (int j = 0; j < 3; ++j) {
    const int g = wave * 3 + j;
    const bool isA = g < 16;
    int rr = isA ? (row0 + g * 16 + lrow) : (col0 + (g - 16) * 16 + lrow);
    const int lim = isA ? M : N;
    if (rr >= lim) rr = 0;
    gp[j] = (isA ? A : Bt) + (size_t)rr * K + sswz;
    ldso[j] = g * 512;
  }

  // fragment-read geometry (R4-proven)
  const int qoff = ((lch ^ ((fr >> 1) & 3)) << 3);
  const int abase = (wm * 64 + fr) * 32 + qoff;
  const int bbase = 8192 + (wn * 64 + fr) * 32 + qoff;

  f32x4 acc[4][4] = {};

  // prologue: stage halves 0,1,2
  #pragma unroll
  for (int h = 0; h < 3; ++h)
    #pragma unroll
    for (int j = 0; j < 3; ++j)
      GLDS16(gp[j] + h * 32, S[h] + ldso[j]);
  asm volatile("s_waitcnt vmcnt(6)" ::: "memory");   // half 0 landed
  __builtin_amdgcn_s_barrier();

  int cur = 0;
  #pragma unroll 1
  for (int h = 0; h < NH; ++h) {
    const unsigned short* sl = S[cur];
    short8 a[4], b[4];
    #pragma unroll
    for (int m = 0; m < 4; ++m)
      a[m] = *reinterpret_cast<const short8*>(sl + abase + m * 512);
    #pragma unroll
    for (int n = 0; n < 4; ++n)
      b[n] = *reinterpret_cast<const short8*>(sl + bbase + n * 512);
    asm volatile("s_waitcnt lgkmcnt(0)" ::: "memory");
    __builtin_amdgcn_sched_barrier(0);
    __builtin_amdgcn_s_barrier();                    // all waves' reads done
    __builtin_amdgcn_s_setprio(1);
    #pragma unroll
    for (int m = 0; m < 4; ++m)
      #pragma unroll
      for (int n = 0; n < 4; ++n)
        acc[m][n] = __builtin_amdgcn_mfma_f32_16x16x32_bf16(a[m], b[n], acc[m][n], 0, 0, 0);
    __builtin_amdgcn_s_setprio(0);
    if (h + 3 < NH) {                                // refill freed slot (= cur)
      const int kc = (h + 3) * 32;
      #pragma unroll
      for (int j = 0; j < 3; ++j) GLDS16(gp[j] + kc, S[cur] + ldso[j]);
      asm volatile("s_waitcnt vmcnt(6)" ::: "memory");   // h+1 landed
    } else if (h + 2 < NH) {
      asm volatile("s_waitcnt vmcnt(3)" ::: "memory");
    } else if (h + 1 < NH) {
      asm volatile("s_waitcnt vmcnt(0)" ::: "memory");
    }
    __builtin_amdgcn_s_barrier();
    cur = (cur == 2) ? 0 : cur + 1;
  }

  // ---- epilogue ----
  const int orow = lch * 4;
  if (MODE == 0) {
    #pragma unroll
    for (int m = 0; m < 4; ++m) {
      #pragma unroll
      for (int n = 0; n < 4; ++n) {
        #pragma unroll
        for (int j = 0; j < 4; ++j) {
          int r = row0 + wm * 64 + m * 16 + orow + j;
          int c = col0 + wn * 64 + n * 16 + fr;
          if (r < M && c < N) {
            float v = acc[m][n][j] + (c < Nbias ? bias[c] : 0.f);
            Cbf[(size_t)r * ldc + c] = f2bf(fmaxf(v, 0.f));
          }
        }
      }
    }
  } else {
    // LDS-staged scatter: 4 bands of 64 rows; 512-B granule f32x4 writes.
    float* Cl = (float*)S;                           // [64][132] f32 = 33.8 KB
    #pragma unroll 1
    for (int p = 0; p < 4; ++p) {
      __builtin_amdgcn_s_barrier();                  // band buffer free
      if (wm == p) {                                 // waves 2p, 2p+1 own band
        #pragma unroll
        for (int m = 0; m < 4; ++m)
          #pragma unroll
          for (int n = 0; n < 4; ++n)
            #pragma unroll
            for (int j = 0; j < 4; ++j) {
              int rr = m * 16 + orow + j;            // 0..63
              int cc = wn * 64 + n * 16 + fr;        // 0..127
              float v = acc[m][n][j] + bias[col0 + cc];
              Cl[rr * 132 + cc] = fmaxf(v, 0.f);
            }
      }
      __builtin_amdgcn_s_barrier();                  // band staged
      #pragma unroll
      for (int u = 0; u < 4; ++u) {
        int unit = tid + u * 512;                    // 64 rows x 32 chunks
        int rr = unit >> 5, ch = unit & 31;
        int r = row0 + p * 64 + rr;
        if (r < M) {
          int iv, rk; rowmap(r, iv, rk);
          int token = order[rk];
          f32x4 v = *reinterpret_cast<const f32x4*>(Cl + rr * 132 + ch * 4);
          *reinterpret_cast<f32x4*>(outf + (size_t)(iv ? OUT_OFF : 0) +
                                    (size_t)token * HDIM + col0 + ch * 4) = v;
        }
      }
    }
  }
}

static inline int swzg(int NP, int NC) { return 8 * NC * ((NP + 7) / 8); }

extern "C" void kernel_launch(void* const* d_in, const int* in_sizes, int n_in,
                              void* d_out, int out_size, void* d_ws, size_t ws_size,
                              hipStream_t stream) {
  const float* keys   = (const float*)d_in[0];
  const float* values = (const float*)d_in[1];
  const float* imp    = (const float*)d_in[2];
  const float* We0    = (const float*)d_in[3];
  const float* be0    = (const float*)d_in[4];
  const float* We1    = (const float*)d_in[5];
  const float* be1    = (const float*)d_in[6];
  const float* Wd0    = (const float*)d_in[7];
  const float* bd0    = (const float*)d_in[8];
  const float* Wd1    = (const float*)d_in[9];
  const float* bd1    = (const float*)d_in[10];

  char* ws = (char*)d_ws;
  int* counts           = (int*)(ws);                       // 64 KB
  int* order            = (int*)(ws + 65536);               // 64 KB
  unsigned short* We0T  = (unsigned short*)(ws + 131072);   // [512][1024]
  unsigned short* We1T  = (unsigned short*)(ws + 1179648);  // [256][512], rows 204+ zero
  unsigned short* Wd1T  = (unsigned short*)(ws + 1441792);  // [512][256], cols 204+ zero
  unsigned short* Wd0T  = (unsigned short*)(ws + 1703936);  // [1024][512]
  unsigned short* Y     = (unsigned short*)(ws + 2752512);  // [26216][512]
  unsigned short* Z     = (unsigned short*)(ws + 29597696); // [22022][256]
  unsigned short* X     = (unsigned short*)(ws + 40872960); // [26216][1024]
  float* outf = (float*)d_out;

  hipMemsetAsync(counts, 0, 65536, stream);
  rank_count<<<dim3(64, 8), 256, 0, stream>>>(imp, counts);
  scatter_order<<<64, 256, 0, stream>>>(counts, order);

  wconv<<<2048, 256, 0, stream>>>(We0T, We0, 512, 1024, 512, 1024);
  wconv<<<512,  256, 0, stream>>>(We1T, We1, 256, 512, 204, 512);
  wconv<<<512,  256, 0, stream>>>(Wd1T, Wd1, 512, 256, 512, 204);
  wconv<<<2048, 256, 0, stream>>>(Wd0T, Wd0, 1024, 512, 1024, 512);

  gather_rows<<<M1ROWS, 256, 0, stream>>>(X, keys, values, order);
  copy_level0<<<6552, 256, 0, stream>>>(outf, keys, values, order);

  // GEMM1: Y = relu(X @ We0 + be0)   [26216 x 1024] x [1024 x 512]
  g2<0, 1024><<<swzg(103, 4), 512, 0, stream>>>(
      X, M1ROWS, We0T, 512, be0, 512, Y, 512, nullptr, nullptr, 103, 4);

  // GEMM2a: Z = relu(Y_l2 @ We1 + be1)  [22022 x 512] x [512 x 256pad]
  g2<0, 512><<<swzg(87, 2), 512, 0, stream>>>(
      Y + (size_t)L2ROW0 * 512, M2ROWS, We1T, 256, be1, 204, Z, 256,
      nullptr, nullptr, 87, 2);

  // GEMM2b: Y_l2 = relu(Z @ Wd1 + bd1)  [22022 x 256] x [256 x 512]
  g2<0, 256><<<swzg(87, 4), 512, 0, stream>>>(
      Z, M2ROWS, Wd1T, 512, bd1, 512, Y + (size_t)L2ROW0 * 512, 512,
      nullptr, nullptr, 87, 4);

  // GEMM3: out = relu(Y @ Wd0 + bd0), LDS-staged f32x4 scatter
  g2<1, 512><<<swzg(103, 8), 512, 0, stream>>>(
      Y, M1ROWS, Wd0T, 1024, bd0, 1024, nullptr, 0, outf, order, 103, 8);
}